// Round 1
// baseline (2773.389 us; speedup 1.0000x reference)
//
#include <hip/hip_runtime.h>
#include <hip/hip_bf16.h>
#include <math.h>

#define BB 32
#define SS 1024
#define DD 256
#define KK 64
#define MM (BB*SS)   // 32768
#define LEPS 1e-5f

// ---------------- big tiled GEMM: C[M,N] = (A[M,256] @ W[256,N] + bias[N]) * scale, opt relu
__global__ __launch_bounds__(256) void gemm_big(const float* __restrict__ A,
                                                const float* __restrict__ W,
                                                const float* __restrict__ bias,
                                                float* __restrict__ C,
                                                int N, float scale, int relu) {
    const int t = threadIdx.x;
    const int m0 = blockIdx.x * 64;
    const int n0 = blockIdx.y * 64;
    __shared__ float As[16][68];
    __shared__ float Bs[16][68];
    const int tx = t & 15, ty = t >> 4;
    float acc[4][4] = {};
    for (int k0 = 0; k0 < 256; k0 += 16) {
        __syncthreads();
        {
            int r = t >> 2, c0 = (t & 3) * 4;
            float4 a4 = *(const float4*)(A + (size_t)(m0 + r) * 256 + k0 + c0);
            As[c0 + 0][r] = a4.x; As[c0 + 1][r] = a4.y;
            As[c0 + 2][r] = a4.z; As[c0 + 3][r] = a4.w;
            int kr = t >> 4, cc0 = (t & 15) * 4;
            float4 b4 = *(const float4*)(W + (size_t)(k0 + kr) * N + n0 + cc0);
            *(float4*)&Bs[kr][cc0] = b4;
        }
        __syncthreads();
#pragma unroll
        for (int kk = 0; kk < 16; kk++) {
            float4 b4 = *(const float4*)&Bs[kk][tx * 4];
            float a0 = As[kk][ty * 4 + 0];
            float a1 = As[kk][ty * 4 + 1];
            float a2 = As[kk][ty * 4 + 2];
            float a3 = As[kk][ty * 4 + 3];
            acc[0][0] += a0 * b4.x; acc[0][1] += a0 * b4.y; acc[0][2] += a0 * b4.z; acc[0][3] += a0 * b4.w;
            acc[1][0] += a1 * b4.x; acc[1][1] += a1 * b4.y; acc[1][2] += a1 * b4.z; acc[1][3] += a1 * b4.w;
            acc[2][0] += a2 * b4.x; acc[2][1] += a2 * b4.y; acc[2][2] += a2 * b4.z; acc[2][3] += a2 * b4.w;
            acc[3][0] += a3 * b4.x; acc[3][1] += a3 * b4.y; acc[3][2] += a3 * b4.z; acc[3][3] += a3 * b4.w;
        }
    }
    float4 bias4 = *(const float4*)(bias + n0 + tx * 4);
#pragma unroll
    for (int i = 0; i < 4; i++) {
        float4 o;
        o.x = (acc[i][0] + bias4.x) * scale;
        o.y = (acc[i][1] + bias4.y) * scale;
        o.z = (acc[i][2] + bias4.z) * scale;
        o.w = (acc[i][3] + bias4.w) * scale;
        if (relu) {
            o.x = fmaxf(o.x, 0.f); o.y = fmaxf(o.y, 0.f);
            o.z = fmaxf(o.z, 0.f); o.w = fmaxf(o.w, 0.f);
        }
        *(float4*)(C + (size_t)(m0 + ty * 4 + i) * N + n0 + tx * 4) = o;
    }
}

// ---------------- small-N GEMM (N<=64): C[M,N] = (A @ W[256,N] + bias)*scale
template <int N>
__global__ __launch_bounds__(256) void gemm_small(const float* __restrict__ A,
                                                  const float* __restrict__ W,
                                                  const float* __restrict__ bias,
                                                  float* __restrict__ C, float scale) {
    const int RPB = 256 / N;
    int t = threadIdx.x;
    int r = t / N, c = t % N;
    size_t row0 = (size_t)blockIdx.x * RPB;
    __shared__ float As[RPB][257];
    for (int i = t; i < RPB * 64; i += 256) {
        int rr = i / 64, cc = (i % 64) * 4;
        float4 v = *(const float4*)(A + (row0 + rr) * 256 + cc);
        As[rr][cc + 0] = v.x; As[rr][cc + 1] = v.y;
        As[rr][cc + 2] = v.z; As[rr][cc + 3] = v.w;
    }
    __syncthreads();
    float acc = 0.f;
#pragma unroll 8
    for (int d = 0; d < 256; d++) acc += As[r][d] * W[d * N + c];
    C[(row0 + r) * N + c] = (acc + bias[c]) * scale;
}

// ---------------- bias gemv: out[r] = x[r,:] . Wb[:,0] + bb[0]
__global__ __launch_bounds__(256) void bias_gemv(const float* __restrict__ X,
                                                 const float* __restrict__ Wb,
                                                 const float* __restrict__ bb,
                                                 float* __restrict__ out) {
    int wave = threadIdx.x >> 6, lane = threadIdx.x & 63;
    size_t row = (size_t)blockIdx.x * 4 + wave;
    float4 xv = *(const float4*)(X + row * 256 + lane * 4);
    float4 wv = *(const float4*)(Wb + lane * 4);
    float p = xv.x * wv.x + xv.y * wv.y + xv.z * wv.z + xv.w * wv.w;
    for (int off = 32; off; off >>= 1) p += __shfl_down(p, off, 64);
    if (lane == 0) out[row] = p + bb[0];
}

// ---------------- fused attention: ob[b,i,:] = sum_j sigmoid(k[b,i].q[b,j] + bias[b,i]) * v[b,j,:]
__global__ __launch_bounds__(256) void attn_kernel(const float* __restrict__ kb,
                                                   const float* __restrict__ qb,
                                                   const float* __restrict__ vb,
                                                   const float* __restrict__ biasb,
                                                   float* __restrict__ ob) {
    const int b = blockIdx.y;
    const int i0 = blockIdx.x * 32;
    const int t = threadIdx.x;
    __shared__ float kT[64][32];
    __shared__ float qT[64][32];
    __shared__ float vs[32][256];
    __shared__ float sS[32][33];
    __shared__ float bia[32];
    // stage kT (transposed) + bias, once per block
    {
        int r = t >> 3;
        int c0 = (t & 7) * 8;
        const float* src = kb + ((size_t)(b * SS + i0 + r)) * 64 + c0;
        float4 v0 = *(const float4*)src;
        float4 v1 = *(const float4*)(src + 4);
        kT[c0 + 0][r] = v0.x; kT[c0 + 1][r] = v0.y; kT[c0 + 2][r] = v0.z; kT[c0 + 3][r] = v0.w;
        kT[c0 + 4][r] = v1.x; kT[c0 + 5][r] = v1.y; kT[c0 + 6][r] = v1.z; kT[c0 + 7][r] = v1.w;
        if (t < 32) bia[t] = biasb[b * SS + i0 + t];
    }
    float acc[4][8] = {};
    const int i4 = t >> 5;   // 0..7
    const int d8 = t & 31;   // 0..31
    for (int j0 = 0; j0 < SS; j0 += 32) {
        __syncthreads();
        {   // stage qT (transposed)
            int r = t >> 3;
            int c0 = (t & 7) * 8;
            const float* src = qb + ((size_t)(b * SS + j0 + r)) * 64 + c0;
            float4 v0 = *(const float4*)src;
            float4 v1 = *(const float4*)(src + 4);
            qT[c0 + 0][r] = v0.x; qT[c0 + 1][r] = v0.y; qT[c0 + 2][r] = v0.z; qT[c0 + 3][r] = v0.w;
            qT[c0 + 4][r] = v1.x; qT[c0 + 5][r] = v1.y; qT[c0 + 6][r] = v1.z; qT[c0 + 7][r] = v1.w;
            // stage v (row-major)
            int vr = t >> 3;
            int vc0 = (t & 7) * 32;
            const float* vsrc = vb + ((size_t)(b * SS + j0 + vr)) * 256 + vc0;
#pragma unroll
            for (int c = 0; c < 32; c += 4)
                *(float4*)&vs[vr][vc0 + c] = *(const float4*)(vsrc + c);
        }
        __syncthreads();
        {   // phase A: scores tile 32x32
            int is = t & 31;
            int jb = t >> 5;  // 0..7
            float sc0 = 0.f, sc1 = 0.f, sc2 = 0.f, sc3 = 0.f;
#pragma unroll 16
            for (int kk = 0; kk < 64; kk++) {
                float kv = kT[kk][is];
                float4 q4 = *(const float4*)&qT[kk][jb * 4];
                sc0 += kv * q4.x; sc1 += kv * q4.y; sc2 += kv * q4.z; sc3 += kv * q4.w;
            }
            float bi = bia[is];
            sS[is][jb * 4 + 0] = 1.f / (1.f + expf(-(sc0 + bi)));
            sS[is][jb * 4 + 1] = 1.f / (1.f + expf(-(sc1 + bi)));
            sS[is][jb * 4 + 2] = 1.f / (1.f + expf(-(sc2 + bi)));
            sS[is][jb * 4 + 3] = 1.f / (1.f + expf(-(sc3 + bi)));
        }
        __syncthreads();
        // phase B: acc += s_tile @ v_tile
#pragma unroll 4
        for (int j = 0; j < 32; j++) {
            float s0 = sS[i4 * 4 + 0][j];
            float s1 = sS[i4 * 4 + 1][j];
            float s2 = sS[i4 * 4 + 2][j];
            float s3 = sS[i4 * 4 + 3][j];
#pragma unroll
            for (int c = 0; c < 8; c++) {
                float vv = vs[j][d8 + 32 * c];
                acc[0][c] += s0 * vv;
                acc[1][c] += s1 * vv;
                acc[2][c] += s2 * vv;
                acc[3][c] += s3 * vv;
            }
        }
    }
#pragma unroll
    for (int ii = 0; ii < 4; ii++) {
        size_t row = (size_t)(b * SS + i0 + i4 * 4 + ii);
#pragma unroll
        for (int c = 0; c < 8; c++) ob[row * 256 + d8 + 32 * c] = acc[ii][c];
    }
}

// ---------------- LN: out[r] = LN(A[r] + Badd[r]) (* gamma + beta if given)
__global__ __launch_bounds__(256) void ln_kernel(const float* __restrict__ A,
                                                 const float* __restrict__ Badd,
                                                 const float* __restrict__ gamma,
                                                 const float* __restrict__ beta,
                                                 float* __restrict__ out) {
    int wave = threadIdx.x >> 6, lane = threadIdx.x & 63;
    size_t row = (size_t)blockIdx.x * 4 + wave;
    float4 av = *(const float4*)(A + row * 256 + lane * 4);
    float4 bv = *(const float4*)(Badd + row * 256 + lane * 4);
    float x0 = av.x + bv.x, x1 = av.y + bv.y, x2 = av.z + bv.z, x3 = av.w + bv.w;
    float s = x0 + x1 + x2 + x3;
    float ss = x0 * x0 + x1 * x1 + x2 * x2 + x3 * x3;
    for (int off = 32; off; off >>= 1) {
        s += __shfl_down(s, off, 64);
        ss += __shfl_down(ss, off, 64);
    }
    s = __shfl(s, 0, 64);
    ss = __shfl(ss, 0, 64);
    float mean = s * (1.f / 256.f);
    float var = ss * (1.f / 256.f) - mean * mean;
    float inv = 1.f / sqrtf(var + LEPS);
    float4 o;
    o.x = (x0 - mean) * inv; o.y = (x1 - mean) * inv;
    o.z = (x2 - mean) * inv; o.w = (x3 - mean) * inv;
    if (gamma != nullptr) {
        float4 g = *(const float4*)(gamma + lane * 4);
        float4 be = *(const float4*)(beta + lane * 4);
        o.x = o.x * g.x + be.x; o.y = o.y * g.y + be.y;
        o.z = o.z * g.z + be.z; o.w = o.w * g.w + be.w;
    }
    *(float4*)(out + row * 256 + lane * 4) = o;
}

// ---------------- pooling: softmax over seq + weighted sum + final linear. One block per batch.
__global__ __launch_bounds__(256) void pool_kernel(const float* __restrict__ pk,
                                                   const float* __restrict__ pv,
                                                   const float* __restrict__ queries,
                                                   const float* __restrict__ W1,
                                                   const float* __restrict__ b1,
                                                   float* __restrict__ out) {
    const int b = blockIdx.x;
    const int t = threadIdx.x;
    __shared__ float sc[4][1024];
    __shared__ float qv[4][16];
    __shared__ float redsum[4];
    __shared__ float r0[256], r1[256];
    if (t < 64) qv[t >> 4][t & 15] = queries[t];
    __syncthreads();
    for (int c = 0; c < 4; c++) {
        int s = c * 256 + t;
        const float* p = pk + ((size_t)b * SS + s) * 16;
        float4 a0 = *(const float4*)p;
        float4 a1 = *(const float4*)(p + 4);
        float4 a2 = *(const float4*)(p + 8);
        float4 a3 = *(const float4*)(p + 12);
#pragma unroll
        for (int h = 0; h < 4; h++) {
            float d = a0.x * qv[h][0] + a0.y * qv[h][1] + a0.z * qv[h][2] + a0.w * qv[h][3]
                    + a1.x * qv[h][4] + a1.y * qv[h][5] + a1.z * qv[h][6] + a1.w * qv[h][7]
                    + a2.x * qv[h][8] + a2.y * qv[h][9] + a2.z * qv[h][10] + a2.w * qv[h][11]
                    + a3.x * qv[h][12] + a3.y * qv[h][13] + a3.z * qv[h][14] + a3.w * qv[h][15];
            sc[h][s] = d;
        }
    }
    __syncthreads();
    {   // softmax per head: wave w handles head w
        int h = t >> 6, lane = t & 63;
        float m = -1e30f;
        for (int s = lane; s < 1024; s += 64) m = fmaxf(m, sc[h][s]);
        for (int off = 32; off; off >>= 1) m = fmaxf(m, __shfl_down(m, off, 64));
        m = __shfl(m, 0, 64);
        float sum = 0.f;
        for (int s = lane; s < 1024; s += 64) {
            float e = expf(sc[h][s] - m);
            sc[h][s] = e;
            sum += e;
        }
        for (int off = 32; off; off >>= 1) sum += __shfl_down(sum, off, 64);
        if (lane == 0) redsum[h] = sum;
    }
    __syncthreads();
    // weighted sum: thread t -> (h = t>>6, d = t&63); pooled flat index = t
    int h = t >> 6, d = t & 63;
    float acc = 0.f;
    for (int s = 0; s < 1024; s++) acc += sc[h][s] * pv[((size_t)b * SS + s) * 64 + d];
    acc /= redsum[h];
    // final linear to 2 outputs
    float p0 = acc * W1[t * 2 + 0];
    float p1 = acc * W1[t * 2 + 1];
    r0[t] = p0; r1[t] = p1;
    __syncthreads();
    for (int off = 128; off > 0; off >>= 1) {
        if (t < off) { r0[t] += r0[t + off]; r1[t] += r1[t + off]; }
        __syncthreads();
    }
    if (t == 0) {
        out[b * 2 + 0] = r0[0] + b1[0];
        out[b * 2 + 1] = r1[0] + b1[1];
    }
}

extern "C" void kernel_launch(void* const* d_in, const int* in_sizes, int n_in,
                              void* d_out, int out_size, void* d_ws, size_t ws_size,
                              hipStream_t stream) {
    const float* input = (const float*)d_in[0];
    const float* eWk = (const float*)d_in[3];
    const float* ebk = (const float*)d_in[4];
    const float* eWq = (const float*)d_in[5];
    const float* ebq = (const float*)d_in[6];
    const float* eWv = (const float*)d_in[7];
    const float* ebv = (const float*)d_in[8];
    const float* eWb = (const float*)d_in[9];
    const float* ebb = (const float*)d_in[10];
    const float* eWff = (const float*)d_in[11];
    const float* ebff = (const float*)d_in[12];
    const float* eg1 = (const float*)d_in[13];
    const float* ebe1 = (const float*)d_in[14];
    const float* pWk = (const float*)d_in[15];
    const float* pbk = (const float*)d_in[16];
    const float* pWv = (const float*)d_in[17];
    const float* pbv = (const float*)d_in[18];
    const float* qrs = (const float*)d_in[19];
    const float* W1 = (const float*)d_in[20];
    const float* b1 = (const float*)d_in[21];
    float* out = (float*)d_out;

    float* ws = (float*)d_ws;
    float* xbuf = ws;                          // M*256
    float* tmp2 = xbuf + (size_t)MM * DD;      // M*256  (attn -> res, in-place LN)
    float* vff  = tmp2 + (size_t)MM * DD;      // M*256  (v then ff)
    float* kbuf = vff + (size_t)MM * DD;       // M*64
    float* qbuf = kbuf + (size_t)MM * 64;      // M*64
    float* bbuf = qbuf + (size_t)MM * 64;      // M

    const float SC = 0.125f;  // 1/sqrt(64)

    for (int l = 0; l < 4; l++) {
        const float* xin = (l == 0) ? input : xbuf;
        gemm_big<<<dim3(MM / 64, 1), 256, 0, stream>>>(xin, eWk + (size_t)l * DD * 64, ebk + l * 64, kbuf, 64, SC, 0);
        gemm_big<<<dim3(MM / 64, 1), 256, 0, stream>>>(xin, eWq + (size_t)l * DD * 64, ebq + l * 64, qbuf, 64, 1.f, 0);
        gemm_big<<<dim3(MM / 64, 4), 256, 0, stream>>>(xin, eWv + (size_t)l * DD * DD, ebv + l * DD, vff, 256, 1.f, 0);
        bias_gemv<<<MM / 4, 256, 0, stream>>>(xin, eWb + (size_t)l * DD, ebb + l, bbuf);
        attn_kernel<<<dim3(SS / 32, BB), 256, 0, stream>>>(kbuf, qbuf, vff, bbuf, tmp2);
        ln_kernel<<<MM / 4, 256, 0, stream>>>(xin, tmp2, eg1 + l * DD, ebe1 + l * DD, tmp2);
        gemm_big<<<dim3(MM / 64, 4), 256, 0, stream>>>(tmp2, eWff + (size_t)l * DD * DD, ebff + l * DD, vff, 256, 1.f, 1);
        ln_kernel<<<MM / 4, 256, 0, stream>>>(tmp2, vff, nullptr, nullptr, xbuf);
    }
    gemm_small<16><<<MM / 16, 256, 0, stream>>>(xbuf, pWk, pbk, kbuf, SC);
    gemm_small<64><<<MM / 4, 256, 0, stream>>>(xbuf, pWv, pbv, qbuf, 1.f);
    pool_kernel<<<BB, 256, 0, stream>>>(kbuf, qbuf, qrs, W1, b1, out);
}

// Round 2
// 1151.875 us; speedup vs baseline: 2.4077x; 2.4077x over previous
//
#include <hip/hip_runtime.h>
#include <hip/hip_bf16.h>
#include <math.h>

#define BB 32
#define SS 1024
#define DD 256
#define MM (BB*SS)   // 32768
#define LEPS 1e-5f

typedef __bf16 bf16x8 __attribute__((ext_vector_type(8)));
typedef float f32x4 __attribute__((ext_vector_type(4)));

// ---------------- big tiled GEMM: C[M,N] = (A[M,256] @ W[256,N] + bias[N]) * scale, opt relu
// OBF=true -> output bf16 row-major, else fp32
template <bool OBF>
__global__ __launch_bounds__(256) void gemm_big(const float* __restrict__ A,
                                                const float* __restrict__ W,
                                                const float* __restrict__ bias,
                                                void* __restrict__ Cv,
                                                int N, float scale, int relu) {
    const int t = threadIdx.x;
    const int m0 = blockIdx.x * 64;
    const int n0 = blockIdx.y * 64;
    __shared__ float As[16][68];
    __shared__ float Bs[16][68];
    const int tx = t & 15, ty = t >> 4;
    float acc[4][4] = {};
    for (int k0 = 0; k0 < 256; k0 += 16) {
        __syncthreads();
        {
            int r = t >> 2, c0 = (t & 3) * 4;
            float4 a4 = *(const float4*)(A + (size_t)(m0 + r) * 256 + k0 + c0);
            As[c0 + 0][r] = a4.x; As[c0 + 1][r] = a4.y;
            As[c0 + 2][r] = a4.z; As[c0 + 3][r] = a4.w;
            int kr = t >> 4, cc0 = (t & 15) * 4;
            float4 b4 = *(const float4*)(W + (size_t)(k0 + kr) * N + n0 + cc0);
            *(float4*)&Bs[kr][cc0] = b4;
        }
        __syncthreads();
#pragma unroll
        for (int kk = 0; kk < 16; kk++) {
            float4 b4 = *(const float4*)&Bs[kk][tx * 4];
            float a0 = As[kk][ty * 4 + 0];
            float a1 = As[kk][ty * 4 + 1];
            float a2 = As[kk][ty * 4 + 2];
            float a3 = As[kk][ty * 4 + 3];
            acc[0][0] += a0 * b4.x; acc[0][1] += a0 * b4.y; acc[0][2] += a0 * b4.z; acc[0][3] += a0 * b4.w;
            acc[1][0] += a1 * b4.x; acc[1][1] += a1 * b4.y; acc[1][2] += a1 * b4.z; acc[1][3] += a1 * b4.w;
            acc[2][0] += a2 * b4.x; acc[2][1] += a2 * b4.y; acc[2][2] += a2 * b4.z; acc[2][3] += a2 * b4.w;
            acc[3][0] += a3 * b4.x; acc[3][1] += a3 * b4.y; acc[3][2] += a3 * b4.z; acc[3][3] += a3 * b4.w;
        }
    }
    float4 bias4 = *(const float4*)(bias + n0 + tx * 4);
#pragma unroll
    for (int i = 0; i < 4; i++) {
        float4 o;
        o.x = (acc[i][0] + bias4.x) * scale;
        o.y = (acc[i][1] + bias4.y) * scale;
        o.z = (acc[i][2] + bias4.z) * scale;
        o.w = (acc[i][3] + bias4.w) * scale;
        if (relu) {
            o.x = fmaxf(o.x, 0.f); o.y = fmaxf(o.y, 0.f);
            o.z = fmaxf(o.z, 0.f); o.w = fmaxf(o.w, 0.f);
        }
        if (OBF) {
            __bf16 tb[4] __attribute__((aligned(8)));
            tb[0] = (__bf16)o.x; tb[1] = (__bf16)o.y; tb[2] = (__bf16)o.z; tb[3] = (__bf16)o.w;
            __bf16* cp = (__bf16*)Cv + (size_t)(m0 + ty * 4 + i) * N + n0 + tx * 4;
            *(uint2*)cp = *(uint2*)tb;
        } else {
            *(float4*)((float*)Cv + (size_t)(m0 + ty * 4 + i) * N + n0 + tx * 4) = o;
        }
    }
}

// ---------------- transpose+pack: vT[b][d][s] = vb[b][s][d]  (bf16 -> bf16)
__global__ __launch_bounds__(256) void transpose_v(const __bf16* __restrict__ vb,
                                                   __bf16* __restrict__ vT) {
    const int b = blockIdx.z, d0 = blockIdx.y * 64, s0 = blockIdx.x * 64;
    const int t = threadIdx.x;
    __shared__ __align__(16) __bf16 Ts[64][64];  // chunk-swizzled rows (8 chunks of 8)
    {
        int s = t >> 2, c0 = (t & 3) * 2;
        const __bf16* src = vb + ((size_t)(b * SS + s0 + s)) * DD + d0 + c0 * 8;
        bf16x8 v0 = *(const bf16x8*)src;
        bf16x8 v1 = *(const bf16x8*)(src + 8);
        *(bf16x8*)&Ts[s][((c0 + 0) ^ (s & 7)) * 8] = v0;
        *(bf16x8*)&Ts[s][((c0 + 1) ^ (s & 7)) * 8] = v1;
    }
    __syncthreads();
    {
        int dr = t >> 2, sc = (t & 3) * 16;
        __bf16 o[16] __attribute__((aligned(16)));
#pragma unroll
        for (int u = 0; u < 16; u++) {
            int row = sc + u;
            o[u] = Ts[row][((dr >> 3) ^ (row & 7)) * 8 + (dr & 7)];
        }
        __bf16* dst = vT + ((size_t)(b * DD + d0 + dr)) * SS + s0 + sc;
        *(bf16x8*)dst = *(bf16x8*)&o[0];
        *(bf16x8*)(dst + 8) = *(bf16x8*)&o[8];
    }
}

// ---------------- bias gemv: out[r] = x[r,:] . Wb[:,0] + bb[0]
__global__ __launch_bounds__(256) void bias_gemv(const float* __restrict__ X,
                                                 const float* __restrict__ Wb,
                                                 const float* __restrict__ bb,
                                                 float* __restrict__ out) {
    int wave = threadIdx.x >> 6, lane = threadIdx.x & 63;
    size_t row = (size_t)blockIdx.x * 4 + wave;
    float4 xv = *(const float4*)(X + row * 256 + lane * 4);
    float4 wv = *(const float4*)(Wb + lane * 4);
    float p = xv.x * wv.x + xv.y * wv.y + xv.z * wv.z + xv.w * wv.w;
    for (int off = 32; off; off >>= 1) p += __shfl_down(p, off, 64);
    if (lane == 0) out[row] = p + bb[0];
}

// ---------------- MFMA fused attention
// ob[b,i,:] = sum_j sigmoid(k[b,i].q[b,j] + bias[b,i]) * v[b,j,:]
// k,q: bf16 [B*S][64] (k pre-scaled); vT: bf16 [B][256][1024]; bias fp32; ob fp32
__global__ __launch_bounds__(256) void attn_mfma(const __bf16* __restrict__ kb,
                                                 const __bf16* __restrict__ qb,
                                                 const __bf16* __restrict__ vT,
                                                 const float* __restrict__ biasb,
                                                 float* __restrict__ ob) {
    // XCD-clustered decode: all 16 i-blocks of a batch share XCD (h%8 == b%8)
    int h = blockIdx.x;
    int blow = h & 7, rest = h >> 3;
    int ib = rest & 15;
    int b = blow + (rest >> 4) * 8;
    const int i0 = ib * 64;
    const int t = threadIdx.x;
    const int w = t >> 6, lane = t & 63;

    __shared__ __align__(16) __bf16 Kl[64][64];   // [i][8 chunks of 8 k], chunk ^= (i&7)
    __shared__ __align__(16) __bf16 Ql[32][64];   // [j][8 chunks of 8 k], chunk ^= (j&7)
    __shared__ __align__(16) __bf16 Vl[256][32];  // [d][4 chunks of 8 j], chunk ^= (d>>1)&3
    __shared__ __align__(16) __bf16 Sl[64][32];   // [i][4 chunks of 8 j], chunk ^= (i>>1)&3
    __shared__ float bsh[64];

    // stage K (once) + bias
    {
        int i = t >> 2, c0 = (t & 3) * 2;
        const __bf16* src = kb + ((size_t)(b * SS + i0 + i)) * 64 + c0 * 8;
        bf16x8 v0 = *(const bf16x8*)src;
        bf16x8 v1 = *(const bf16x8*)(src + 8);
        *(bf16x8*)&Kl[i][((c0 + 0) ^ (i & 7)) * 8] = v0;
        *(bf16x8*)&Kl[i][((c0 + 1) ^ (i & 7)) * 8] = v1;
        if (t < 64) bsh[t] = biasb[b * SS + i0 + t];
    }

    f32x4 acc[4][4] = {};  // [iq][db] : rows i0+iq*16.., cols w*64+db*16..

    for (int j0 = 0; j0 < SS; j0 += 32) {
        __syncthreads();
        {   // stage Q tile [32][64]
            int j = t >> 3, c = t & 7;
            bf16x8 v = *(const bf16x8*)(qb + ((size_t)(b * SS + j0 + j)) * 64 + c * 8);
            *(bf16x8*)&Ql[j][(c ^ (j & 7)) * 8] = v;
        }
        {   // stage vT tile [256][32]
            const __bf16* src = vT + ((size_t)b * 256 + t) * SS + j0;
#pragma unroll
            for (int c = 0; c < 4; c++) {
                bf16x8 v = *(const bf16x8*)(src + c * 8);
                *(bf16x8*)&Vl[t][(c ^ ((t >> 1) & 3)) * 8] = v;
            }
        }
        __syncthreads();
        // ---- S phase: wave w computes S rows [w*16, w*16+16) x all 32 j
        {
            const int iq = w;
#pragma unroll
            for (int jq = 0; jq < 2; jq++) {
                f32x4 sacc = {0.f, 0.f, 0.f, 0.f};
#pragma unroll
                for (int ks = 0; ks < 2; ks++) {
                    int i = iq * 16 + (lane & 15);
                    int ck = ks * 4 + (lane >> 4);
                    bf16x8 a = *(const bf16x8*)&Kl[i][(ck ^ (i & 7)) * 8];
                    int j = jq * 16 + (lane & 15);
                    bf16x8 bq = *(const bf16x8*)&Ql[j][(ck ^ (j & 7)) * 8];
                    sacc = __builtin_amdgcn_mfma_f32_16x16x32_bf16(a, bq, sacc, 0, 0, 0);
                }
                int jcol = jq * 16 + (lane & 15);
#pragma unroll
                for (int r = 0; r < 4; r++) {
                    int irow = iq * 16 + (lane >> 4) * 4 + r;
                    float x = sacc[r] + bsh[irow];
                    float sg = 1.f / (1.f + __expf(-x));
                    Sl[irow][(((jcol >> 3) ^ ((irow >> 1) & 3)) * 8) + (jcol & 7)] = (__bf16)sg;
                }
            }
        }
        __syncthreads();
        // ---- PV phase: wave w owns d-slice [w*64, w*64+64)
#pragma unroll
        for (int iq = 0; iq < 4; iq++) {
            int i = iq * 16 + (lane & 15);
            int cj = lane >> 4;
            bf16x8 as = *(const bf16x8*)&Sl[i][(cj ^ ((i >> 1) & 3)) * 8];
#pragma unroll
            for (int db = 0; db < 4; db++) {
                int d = w * 64 + db * 16 + (lane & 15);
                bf16x8 bv = *(const bf16x8*)&Vl[d][(cj ^ ((d >> 1) & 3)) * 8];
                acc[iq][db] = __builtin_amdgcn_mfma_f32_16x16x32_bf16(as, bv, acc[iq][db], 0, 0, 0);
            }
        }
    }
    // epilogue: D layout col = lane&15, row = (lane>>4)*4 + r
#pragma unroll
    for (int iq = 0; iq < 4; iq++) {
#pragma unroll
        for (int r = 0; r < 4; r++) {
            int irow = i0 + iq * 16 + (lane >> 4) * 4 + r;
            float* dst = ob + ((size_t)(b * SS + irow)) * 256 + w * 64 + (lane & 15);
            dst[0]  = acc[iq][0][r];
            dst[16] = acc[iq][1][r];
            dst[32] = acc[iq][2][r];
            dst[48] = acc[iq][3][r];
        }
    }
}

// ---------------- LN: out[r] = LN(A[r] + Badd[r]) (* gamma + beta if given)
__global__ __launch_bounds__(256) void ln_kernel(const float* __restrict__ A,
                                                 const float* __restrict__ Badd,
                                                 const float* __restrict__ gamma,
                                                 const float* __restrict__ beta,
                                                 float* __restrict__ out) {
    int wave = threadIdx.x >> 6, lane = threadIdx.x & 63;
    size_t row = (size_t)blockIdx.x * 4 + wave;
    float4 av = *(const float4*)(A + row * 256 + lane * 4);
    float4 bv = *(const float4*)(Badd + row * 256 + lane * 4);
    float x0 = av.x + bv.x, x1 = av.y + bv.y, x2 = av.z + bv.z, x3 = av.w + bv.w;
    float s = x0 + x1 + x2 + x3;
    float ss = x0 * x0 + x1 * x1 + x2 * x2 + x3 * x3;
    for (int off = 32; off; off >>= 1) {
        s += __shfl_down(s, off, 64);
        ss += __shfl_down(ss, off, 64);
    }
    s = __shfl(s, 0, 64);
    ss = __shfl(ss, 0, 64);
    float mean = s * (1.f / 256.f);
    float var = ss * (1.f / 256.f) - mean * mean;
    float inv = 1.f / sqrtf(var + LEPS);
    float4 o;
    o.x = (x0 - mean) * inv; o.y = (x1 - mean) * inv;
    o.z = (x2 - mean) * inv; o.w = (x3 - mean) * inv;
    if (gamma != nullptr) {
        float4 g = *(const float4*)(gamma + lane * 4);
        float4 be = *(const float4*)(beta + lane * 4);
        o.x = o.x * g.x + be.x; o.y = o.y * g.y + be.y;
        o.z = o.z * g.z + be.z; o.w = o.w * g.w + be.w;
    }
    *(float4*)(out + row * 256 + lane * 4) = o;
}

// ---------------- small-N GEMM (N<=64): C[M,N] = (A @ W[256,N] + bias)*scale
template <int N>
__global__ __launch_bounds__(256) void gemm_small(const float* __restrict__ A,
                                                  const float* __restrict__ W,
                                                  const float* __restrict__ bias,
                                                  float* __restrict__ C, float scale) {
    const int RPB = 256 / N;
    int t = threadIdx.x;
    int r = t / N, c = t % N;
    size_t row0 = (size_t)blockIdx.x * RPB;
    __shared__ float As[RPB][257];
    for (int i = t; i < RPB * 64; i += 256) {
        int rr = i / 64, cc = (i % 64) * 4;
        float4 v = *(const float4*)(A + (row0 + rr) * 256 + cc);
        As[rr][cc + 0] = v.x; As[rr][cc + 1] = v.y;
        As[rr][cc + 2] = v.z; As[rr][cc + 3] = v.w;
    }
    __syncthreads();
    float acc = 0.f;
#pragma unroll 8
    for (int d = 0; d < 256; d++) acc += As[r][d] * W[d * N + c];
    C[(row0 + r) * N + c] = (acc + bias[c]) * scale;
}

// ---------------- pooling: softmax over seq + weighted sum + final linear. One block per batch.
__global__ __launch_bounds__(256) void pool_kernel(const float* __restrict__ pk,
                                                   const float* __restrict__ pv,
                                                   const float* __restrict__ queries,
                                                   const float* __restrict__ W1,
                                                   const float* __restrict__ b1,
                                                   float* __restrict__ out) {
    const int b = blockIdx.x;
    const int t = threadIdx.x;
    __shared__ float sc[4][1024];
    __shared__ float qv[4][16];
    __shared__ float redsum[4];
    __shared__ float r0[256], r1[256];
    if (t < 64) qv[t >> 4][t & 15] = queries[t];
    __syncthreads();
    for (int c = 0; c < 4; c++) {
        int s = c * 256 + t;
        const float* p = pk + ((size_t)b * SS + s) * 16;
        float4 a0 = *(const float4*)p;
        float4 a1 = *(const float4*)(p + 4);
        float4 a2 = *(const float4*)(p + 8);
        float4 a3 = *(const float4*)(p + 12);
#pragma unroll
        for (int hh = 0; hh < 4; hh++) {
            float d = a0.x * qv[hh][0] + a0.y * qv[hh][1] + a0.z * qv[hh][2] + a0.w * qv[hh][3]
                    + a1.x * qv[hh][4] + a1.y * qv[hh][5] + a1.z * qv[hh][6] + a1.w * qv[hh][7]
                    + a2.x * qv[hh][8] + a2.y * qv[hh][9] + a2.z * qv[hh][10] + a2.w * qv[hh][11]
                    + a3.x * qv[hh][12] + a3.y * qv[hh][13] + a3.z * qv[hh][14] + a3.w * qv[hh][15];
            sc[hh][s] = d;
        }
    }
    __syncthreads();
    {
        int hh = t >> 6, lane = t & 63;
        float m = -1e30f;
        for (int s = lane; s < 1024; s += 64) m = fmaxf(m, sc[hh][s]);
        for (int off = 32; off; off >>= 1) m = fmaxf(m, __shfl_down(m, off, 64));
        m = __shfl(m, 0, 64);
        float sum = 0.f;
        for (int s = lane; s < 1024; s += 64) {
            float e = expf(sc[hh][s] - m);
            sc[hh][s] = e;
            sum += e;
        }
        for (int off = 32; off; off >>= 1) sum += __shfl_down(sum, off, 64);
        if (lane == 0) redsum[hh] = sum;
    }
    __syncthreads();
    int hh = t >> 6, d = t & 63;
    float acc = 0.f;
    for (int s = 0; s < 1024; s++) acc += sc[hh][s] * pv[((size_t)b * SS + s) * 64 + d];
    acc /= redsum[hh];
    float p0 = acc * W1[t * 2 + 0];
    float p1 = acc * W1[t * 2 + 1];
    r0[t] = p0; r1[t] = p1;
    __syncthreads();
    for (int off = 128; off > 0; off >>= 1) {
        if (t < off) { r0[t] += r0[t + off]; r1[t] += r1[t + off]; }
        __syncthreads();
    }
    if (t == 0) {
        out[b * 2 + 0] = r0[0] + b1[0];
        out[b * 2 + 1] = r1[0] + b1[1];
    }
}

extern "C" void kernel_launch(void* const* d_in, const int* in_sizes, int n_in,
                              void* d_out, int out_size, void* d_ws, size_t ws_size,
                              hipStream_t stream) {
    const float* input = (const float*)d_in[0];
    const float* eWk = (const float*)d_in[3];
    const float* ebk = (const float*)d_in[4];
    const float* eWq = (const float*)d_in[5];
    const float* ebq = (const float*)d_in[6];
    const float* eWv = (const float*)d_in[7];
    const float* ebv = (const float*)d_in[8];
    const float* eWb = (const float*)d_in[9];
    const float* ebb = (const float*)d_in[10];
    const float* eWff = (const float*)d_in[11];
    const float* ebff = (const float*)d_in[12];
    const float* eg1 = (const float*)d_in[13];
    const float* ebe1 = (const float*)d_in[14];
    const float* pWk = (const float*)d_in[15];
    const float* pbk = (const float*)d_in[16];
    const float* pWv = (const float*)d_in[17];
    const float* pbv = (const float*)d_in[18];
    const float* qrs = (const float*)d_in[19];
    const float* W1 = (const float*)d_in[20];
    const float* b1 = (const float*)d_in[21];
    float* out = (float*)d_out;

    float* ws = (float*)d_ws;
    float* xbuf = ws;                            // MM*256 f32
    float* tmp2 = xbuf + (size_t)MM * DD;        // MM*256 f32
    float* vreg = tmp2 + (size_t)MM * DD;        // MM*256 f32 region (aliased below)
    __bf16* vbf = (__bf16*)vreg;                 // MM*256 bf16 (first half of vreg)
    __bf16* vTb = vbf + (size_t)MM * DD;         // B*256*1024 bf16 (second half of vreg)
    float* ffbuf = vreg;                         // MM*256 f32 (reuses vreg after attn)
    __bf16* kbf = (__bf16*)(vreg + (size_t)MM * DD);   // MM*64 bf16
    __bf16* qbf = kbf + (size_t)MM * 64;               // MM*64 bf16
    float* bbuf = (float*)(qbf + (size_t)MM * 64);     // MM f32

    const float SC = 0.125f;  // 1/sqrt(64)

    for (int l = 0; l < 4; l++) {
        const float* xin = (l == 0) ? input : xbuf;
        gemm_big<true><<<dim3(MM / 64, 1), 256, 0, stream>>>(xin, eWk + (size_t)l * DD * 64, ebk + l * 64, kbf, 64, SC, 0);
        gemm_big<true><<<dim3(MM / 64, 1), 256, 0, stream>>>(xin, eWq + (size_t)l * DD * 64, ebq + l * 64, qbf, 64, 1.f, 0);
        gemm_big<true><<<dim3(MM / 64, 4), 256, 0, stream>>>(xin, eWv + (size_t)l * DD * DD, ebv + l * DD, vbf, 256, 1.f, 0);
        transpose_v<<<dim3(SS / 64, DD / 64, BB), 256, 0, stream>>>(vbf, vTb);
        bias_gemv<<<MM / 4, 256, 0, stream>>>(xin, eWb + (size_t)l * DD, ebb + l, bbuf);
        attn_mfma<<<dim3(512, 1), 256, 0, stream>>>(kbf, qbf, vTb, bbuf, tmp2);
        ln_kernel<<<MM / 4, 256, 0, stream>>>(xin, tmp2, eg1 + l * DD, ebe1 + l * DD, tmp2);
        gemm_big<false><<<dim3(MM / 64, 4), 256, 0, stream>>>(tmp2, eWff + (size_t)l * DD * DD, ebff + l * DD, ffbuf, 256, 1.f, 1);
        ln_kernel<<<MM / 4, 256, 0, stream>>>(tmp2, ffbuf, nullptr, nullptr, xbuf);
    }
    // pooling scratch in tmp2 (fp32): pk [MM*16], pv [MM*64]
    float* pkbuf = tmp2;
    float* pvbuf = tmp2 + (size_t)MM * 16;
    gemm_small<16><<<MM / 16, 256, 0, stream>>>(xbuf, pWk, pbk, pkbuf, SC);
    gemm_small<64><<<MM / 4, 256, 0, stream>>>(xbuf, pWv, pbv, pvbuf, 1.f);
    pool_kernel<<<BB, 256, 0, stream>>>(pkbuf, pvbuf, qrs, W1, b1, out);
}

// Round 3
// 659.483 us; speedup vs baseline: 4.2054x; 1.7466x over previous
//
#include <hip/hip_runtime.h>
#include <hip/hip_bf16.h>
#include <math.h>

#define BB 32
#define SS 1024
#define DD 256
#define MM (BB*SS)   // 32768
#define LEPS 1e-5f

typedef __bf16 bf16x8 __attribute__((ext_vector_type(8)));
typedef float f32x4 __attribute__((ext_vector_type(4)));

// ---------------- weight cast+transpose: WT[l][n][k] = W[l][k][n]*scale (fp32->bf16), K=256
__global__ __launch_bounds__(256) void cast_wt(const float* __restrict__ W,
                                               __bf16* __restrict__ WT,
                                               int N, float scale) {
    int n = blockIdx.x, l = blockIdx.z, k = threadIdx.x;
    size_t stride = (size_t)256 * N;
    WT[stride * l + (size_t)n * 256 + k] = (__bf16)(W[stride * l + (size_t)k * N + n] * scale);
}

// ---------------- cast fp32 -> bf16, 8 elems/thread
__global__ __launch_bounds__(256) void cast_x(const float* __restrict__ x, __bf16* __restrict__ xb) {
    size_t i = ((size_t)blockIdx.x * 256 + threadIdx.x) * 8;
    float4 a = *(const float4*)(x + i);
    float4 b = *(const float4*)(x + i + 4);
    __bf16 o[8] __attribute__((aligned(16)));
    o[0] = (__bf16)a.x; o[1] = (__bf16)a.y; o[2] = (__bf16)a.z; o[3] = (__bf16)a.w;
    o[4] = (__bf16)b.x; o[5] = (__bf16)b.y; o[6] = (__bf16)b.z; o[7] = (__bf16)b.w;
    *(bf16x8*)(xb + i) = *(bf16x8*)o;
}

// ---------------- MFMA GEMM: C[M,N] = A[M,256] @ WT[N,256]^T + bias*bscale, opt relu
// BM=128, BK=64. BN in {128,64,16}. 4 waves.
template <int BN, bool OBF>
__global__ __launch_bounds__(256) void gemm_mfma(const __bf16* __restrict__ A,
                                                 const __bf16* __restrict__ WT,
                                                 const float* __restrict__ bias,
                                                 float bscale, int relu,
                                                 void* __restrict__ Cv, int N) {
    constexpr int MR = (BN == 128) ? 4 : 2;
    constexpr int NC = (BN == 128) ? 4 : BN / 16;
    const int t = threadIdx.x;
    const int w = t >> 6, lane = t & 63;
    const int m0 = blockIdx.x * 128;
    const int n0 = blockIdx.y * BN;
    const int wr = (BN == 128) ? (w >> 1) * 64 : w * 32;
    const int wc = (BN == 128) ? (w & 1) * 64 : 0;
    __shared__ __align__(16) __bf16 Al[128][64];   // row i, 8 chunks of 8, chunk ^= (i&7)
    __shared__ __align__(16) __bf16 Wl[BN][64];    // row n, same swizzle
    f32x4 acc[MR][NC] = {};

    for (int k0 = 0; k0 < 256; k0 += 64) {
        __syncthreads();
        {   // stage A tile [128][64]
            int r = t >> 1, half = t & 1;
            const __bf16* src = A + (size_t)(m0 + r) * 256 + k0 + half * 32;
            bf16x8 v0 = *(const bf16x8*)(src);
            bf16x8 v1 = *(const bf16x8*)(src + 8);
            bf16x8 v2 = *(const bf16x8*)(src + 16);
            bf16x8 v3 = *(const bf16x8*)(src + 24);
            int cb = half * 4;
            *(bf16x8*)&Al[r][((cb + 0) ^ (r & 7)) * 8] = v0;
            *(bf16x8*)&Al[r][((cb + 1) ^ (r & 7)) * 8] = v1;
            *(bf16x8*)&Al[r][((cb + 2) ^ (r & 7)) * 8] = v2;
            *(bf16x8*)&Al[r][((cb + 3) ^ (r & 7)) * 8] = v3;
        }
        if (BN == 128) {   // stage W tile [128][64], same pattern as A
            int r = t >> 1, half = t & 1;
            const __bf16* src = WT + (size_t)(n0 + r) * 256 + k0 + half * 32;
            bf16x8 v0 = *(const bf16x8*)(src);
            bf16x8 v1 = *(const bf16x8*)(src + 8);
            bf16x8 v2 = *(const bf16x8*)(src + 16);
            bf16x8 v3 = *(const bf16x8*)(src + 24);
            int cb = half * 4;
            *(bf16x8*)&Wl[r][((cb + 0) ^ (r & 7)) * 8] = v0;
            *(bf16x8*)&Wl[r][((cb + 1) ^ (r & 7)) * 8] = v1;
            *(bf16x8*)&Wl[r][((cb + 2) ^ (r & 7)) * 8] = v2;
            *(bf16x8*)&Wl[r][((cb + 3) ^ (r & 7)) * 8] = v3;
        } else if (BN == 64) {
            int n = t >> 2, q = t & 3;
            const __bf16* src = WT + (size_t)(n0 + n) * 256 + k0 + q * 16;
            bf16x8 v0 = *(const bf16x8*)src;
            bf16x8 v1 = *(const bf16x8*)(src + 8);
            *(bf16x8*)&Wl[n][((q * 2 + 0) ^ (n & 7)) * 8] = v0;
            *(bf16x8*)&Wl[n][((q * 2 + 1) ^ (n & 7)) * 8] = v1;
        } else {  // BN==16
            if (t < 128) {
                int n = t >> 3, c = t & 7;
                bf16x8 v = *(const bf16x8*)(WT + (size_t)(n0 + n) * 256 + k0 + c * 8);
                *(bf16x8*)&Wl[n][(c ^ (n & 7)) * 8] = v;
            }
        }
        __syncthreads();
#pragma unroll
        for (int ks = 0; ks < 2; ks++) {
            int c = ks * 4 + (lane >> 4);
            bf16x8 af[MR];
#pragma unroll
            for (int mf = 0; mf < MR; mf++) {
                int i = wr + mf * 16 + (lane & 15);
                af[mf] = *(const bf16x8*)&Al[i][(c ^ (i & 7)) * 8];
            }
#pragma unroll
            for (int nf = 0; nf < NC; nf++) {
                int n = wc + nf * 16 + (lane & 15);
                bf16x8 bfr = *(const bf16x8*)&Wl[n][(c ^ (n & 7)) * 8];
#pragma unroll
                for (int mf = 0; mf < MR; mf++)
                    acc[mf][nf] = __builtin_amdgcn_mfma_f32_16x16x32_bf16(af[mf], bfr, acc[mf][nf], 0, 0, 0);
            }
        }
    }
    // epilogue: D layout col = lane&15, row = (lane>>4)*4 + r
#pragma unroll
    for (int mf = 0; mf < MR; mf++) {
#pragma unroll
        for (int nf = 0; nf < NC; nf++) {
            int col = n0 + wc + nf * 16 + (lane & 15);
            float bz = bias[col] * bscale;
#pragma unroll
            for (int r = 0; r < 4; r++) {
                int row = m0 + wr + mf * 16 + (lane >> 4) * 4 + r;
                float v = acc[mf][nf][r] + bz;
                if (relu) v = fmaxf(v, 0.f);
                if (OBF) ((__bf16*)Cv)[(size_t)row * N + col] = (__bf16)v;
                else ((float*)Cv)[(size_t)row * N + col] = v;
            }
        }
    }
}

// ---------------- transpose+pack: vT[b][d][s] = vb[b][s][d]  (bf16 -> bf16)
__global__ __launch_bounds__(256) void transpose_v(const __bf16* __restrict__ vb,
                                                   __bf16* __restrict__ vT) {
    const int b = blockIdx.z, d0 = blockIdx.y * 64, s0 = blockIdx.x * 64;
    const int t = threadIdx.x;
    __shared__ __align__(16) __bf16 Ts[64][64];
    {
        int s = t >> 2, c0 = (t & 3) * 2;
        const __bf16* src = vb + ((size_t)(b * SS + s0 + s)) * DD + d0 + c0 * 8;
        bf16x8 v0 = *(const bf16x8*)src;
        bf16x8 v1 = *(const bf16x8*)(src + 8);
        *(bf16x8*)&Ts[s][((c0 + 0) ^ (s & 7)) * 8] = v0;
        *(bf16x8*)&Ts[s][((c0 + 1) ^ (s & 7)) * 8] = v1;
    }
    __syncthreads();
    {
        int dr = t >> 2, sc = (t & 3) * 16;
        __bf16 o[16] __attribute__((aligned(16)));
#pragma unroll
        for (int u = 0; u < 16; u++) {
            int row = sc + u;
            o[u] = Ts[row][((dr >> 3) ^ (row & 7)) * 8 + (dr & 7)];
        }
        __bf16* dst = vT + ((size_t)(b * DD + d0 + dr)) * SS + s0 + sc;
        *(bf16x8*)dst = *(bf16x8*)&o[0];
        *(bf16x8*)(dst + 8) = *(bf16x8*)&o[8];
    }
}

// ---------------- bias gemv: out[r] = x[r,:] . Wb[:,0] + bb[0]
__global__ __launch_bounds__(256) void bias_gemv(const float* __restrict__ X,
                                                 const float* __restrict__ Wb,
                                                 const float* __restrict__ bb,
                                                 float* __restrict__ out) {
    int wave = threadIdx.x >> 6, lane = threadIdx.x & 63;
    size_t row = (size_t)blockIdx.x * 4 + wave;
    float4 xv = *(const float4*)(X + row * 256 + lane * 4);
    float4 wv = *(const float4*)(Wb + lane * 4);
    float p = xv.x * wv.x + xv.y * wv.y + xv.z * wv.z + xv.w * wv.w;
    for (int off = 32; off; off >>= 1) p += __shfl_down(p, off, 64);
    if (lane == 0) out[row] = p + bb[0];
}

// ---------------- MFMA fused attention (unchanged from round 2)
__global__ __launch_bounds__(256) void attn_mfma(const __bf16* __restrict__ kb,
                                                 const __bf16* __restrict__ qb,
                                                 const __bf16* __restrict__ vT,
                                                 const float* __restrict__ biasb,
                                                 float* __restrict__ ob) {
    int h = blockIdx.x;
    int blow = h & 7, rest = h >> 3;
    int ib = rest & 15;
    int b = blow + (rest >> 4) * 8;
    const int i0 = ib * 64;
    const int t = threadIdx.x;
    const int w = t >> 6, lane = t & 63;

    __shared__ __align__(16) __bf16 Kl[64][64];
    __shared__ __align__(16) __bf16 Ql[32][64];
    __shared__ __align__(16) __bf16 Vl[256][32];
    __shared__ __align__(16) __bf16 Sl[64][32];
    __shared__ float bsh[64];

    {
        int i = t >> 2, c0 = (t & 3) * 2;
        const __bf16* src = kb + ((size_t)(b * SS + i0 + i)) * 64 + c0 * 8;
        bf16x8 v0 = *(const bf16x8*)src;
        bf16x8 v1 = *(const bf16x8*)(src + 8);
        *(bf16x8*)&Kl[i][((c0 + 0) ^ (i & 7)) * 8] = v0;
        *(bf16x8*)&Kl[i][((c0 + 1) ^ (i & 7)) * 8] = v1;
        if (t < 64) bsh[t] = biasb[b * SS + i0 + t];
    }

    f32x4 acc[4][4] = {};

    for (int j0 = 0; j0 < SS; j0 += 32) {
        __syncthreads();
        {
            int j = t >> 3, c = t & 7;
            bf16x8 v = *(const bf16x8*)(qb + ((size_t)(b * SS + j0 + j)) * 64 + c * 8);
            *(bf16x8*)&Ql[j][(c ^ (j & 7)) * 8] = v;
        }
        {
            const __bf16* src = vT + ((size_t)b * 256 + t) * SS + j0;
#pragma unroll
            for (int c = 0; c < 4; c++) {
                bf16x8 v = *(const bf16x8*)(src + c * 8);
                *(bf16x8*)&Vl[t][(c ^ ((t >> 1) & 3)) * 8] = v;
            }
        }
        __syncthreads();
        {
            const int iq = w;
#pragma unroll
            for (int jq = 0; jq < 2; jq++) {
                f32x4 sacc = {0.f, 0.f, 0.f, 0.f};
#pragma unroll
                for (int ks = 0; ks < 2; ks++) {
                    int i = iq * 16 + (lane & 15);
                    int ck = ks * 4 + (lane >> 4);
                    bf16x8 a = *(const bf16x8*)&Kl[i][(ck ^ (i & 7)) * 8];
                    int j = jq * 16 + (lane & 15);
                    bf16x8 bq = *(const bf16x8*)&Ql[j][(ck ^ (j & 7)) * 8];
                    sacc = __builtin_amdgcn_mfma_f32_16x16x32_bf16(a, bq, sacc, 0, 0, 0);
                }
                int jcol = jq * 16 + (lane & 15);
#pragma unroll
                for (int r = 0; r < 4; r++) {
                    int irow = iq * 16 + (lane >> 4) * 4 + r;
                    float x = sacc[r] + bsh[irow];
                    float sg = 1.f / (1.f + __expf(-x));
                    Sl[irow][(((jcol >> 3) ^ ((irow >> 1) & 3)) * 8) + (jcol & 7)] = (__bf16)sg;
                }
            }
        }
        __syncthreads();
#pragma unroll
        for (int iq = 0; iq < 4; iq++) {
            int i = iq * 16 + (lane & 15);
            int cj = lane >> 4;
            bf16x8 as = *(const bf16x8*)&Sl[i][(cj ^ ((i >> 1) & 3)) * 8];
#pragma unroll
            for (int db = 0; db < 4; db++) {
                int d = w * 64 + db * 16 + (lane & 15);
                bf16x8 bv = *(const bf16x8*)&Vl[d][(cj ^ ((d >> 1) & 3)) * 8];
                acc[iq][db] = __builtin_amdgcn_mfma_f32_16x16x32_bf16(as, bv, acc[iq][db], 0, 0, 0);
            }
        }
    }
#pragma unroll
    for (int iq = 0; iq < 4; iq++) {
#pragma unroll
        for (int r = 0; r < 4; r++) {
            int irow = i0 + iq * 16 + (lane >> 4) * 4 + r;
            float* dst = ob + ((size_t)(b * SS + irow)) * 256 + w * 64 + (lane & 15);
            dst[0]  = acc[iq][0][r];
            dst[16] = acc[iq][1][r];
            dst[32] = acc[iq][2][r];
            dst[48] = acc[iq][3][r];
        }
    }
}

// ---------------- LN: out = LN(A + Badd) (*gamma+beta opt); dual fp32 + bf16 store
__global__ __launch_bounds__(256) void ln_kernel(const float* __restrict__ A,
                                                 const float* __restrict__ Badd,
                                                 const float* __restrict__ gamma,
                                                 const float* __restrict__ beta,
                                                 float* __restrict__ out,
                                                 __bf16* __restrict__ outb) {
    int wave = threadIdx.x >> 6, lane = threadIdx.x & 63;
    size_t row = (size_t)blockIdx.x * 4 + wave;
    float4 av = *(const float4*)(A + row * 256 + lane * 4);
    float4 bv = *(const float4*)(Badd + row * 256 + lane * 4);
    float x0 = av.x + bv.x, x1 = av.y + bv.y, x2 = av.z + bv.z, x3 = av.w + bv.w;
    float s = x0 + x1 + x2 + x3;
    float ss = x0 * x0 + x1 * x1 + x2 * x2 + x3 * x3;
    for (int off = 32; off; off >>= 1) {
        s += __shfl_down(s, off, 64);
        ss += __shfl_down(ss, off, 64);
    }
    s = __shfl(s, 0, 64);
    ss = __shfl(ss, 0, 64);
    float mean = s * (1.f / 256.f);
    float var = ss * (1.f / 256.f) - mean * mean;
    float inv = 1.f / sqrtf(var + LEPS);
    float4 o;
    o.x = (x0 - mean) * inv; o.y = (x1 - mean) * inv;
    o.z = (x2 - mean) * inv; o.w = (x3 - mean) * inv;
    if (gamma != nullptr) {
        float4 g = *(const float4*)(gamma + lane * 4);
        float4 be = *(const float4*)(beta + lane * 4);
        o.x = o.x * g.x + be.x; o.y = o.y * g.y + be.y;
        o.z = o.z * g.z + be.z; o.w = o.w * g.w + be.w;
    }
    *(float4*)(out + row * 256 + lane * 4) = o;
    if (outb != nullptr) {
        __bf16 ob[4] __attribute__((aligned(8)));
        ob[0] = (__bf16)o.x; ob[1] = (__bf16)o.y; ob[2] = (__bf16)o.z; ob[3] = (__bf16)o.w;
        *(uint2*)(outb + row * 256 + lane * 4) = *(uint2*)ob;
    }
}

// ---------------- pooling (unchanged)
__global__ __launch_bounds__(256) void pool_kernel(const float* __restrict__ pk,
                                                   const float* __restrict__ pv,
                                                   const float* __restrict__ queries,
                                                   const float* __restrict__ W1,
                                                   const float* __restrict__ b1,
                                                   float* __restrict__ out) {
    const int b = blockIdx.x;
    const int t = threadIdx.x;
    __shared__ float sc[4][1024];
    __shared__ float qv[4][16];
    __shared__ float redsum[4];
    __shared__ float r0[256], r1[256];
    if (t < 64) qv[t >> 4][t & 15] = queries[t];
    __syncthreads();
    for (int c = 0; c < 4; c++) {
        int s = c * 256 + t;
        const float* p = pk + ((size_t)b * SS + s) * 16;
        float4 a0 = *(const float4*)p;
        float4 a1 = *(const float4*)(p + 4);
        float4 a2 = *(const float4*)(p + 8);
        float4 a3 = *(const float4*)(p + 12);
#pragma unroll
        for (int hh = 0; hh < 4; hh++) {
            float d = a0.x * qv[hh][0] + a0.y * qv[hh][1] + a0.z * qv[hh][2] + a0.w * qv[hh][3]
                    + a1.x * qv[hh][4] + a1.y * qv[hh][5] + a1.z * qv[hh][6] + a1.w * qv[hh][7]
                    + a2.x * qv[hh][8] + a2.y * qv[hh][9] + a2.z * qv[hh][10] + a2.w * qv[hh][11]
                    + a3.x * qv[hh][12] + a3.y * qv[hh][13] + a3.z * qv[hh][14] + a3.w * qv[hh][15];
            sc[hh][s] = d;
        }
    }
    __syncthreads();
    {
        int hh = t >> 6, lane = t & 63;
        float m = -1e30f;
        for (int s = lane; s < 1024; s += 64) m = fmaxf(m, sc[hh][s]);
        for (int off = 32; off; off >>= 1) m = fmaxf(m, __shfl_down(m, off, 64));
        m = __shfl(m, 0, 64);
        float sum = 0.f;
        for (int s = lane; s < 1024; s += 64) {
            float e = expf(sc[hh][s] - m);
            sc[hh][s] = e;
            sum += e;
        }
        for (int off = 32; off; off >>= 1) sum += __shfl_down(sum, off, 64);
        if (lane == 0) redsum[hh] = sum;
    }
    __syncthreads();
    int hh = t >> 6, d = t & 63;
    float acc = 0.f;
    for (int s = 0; s < 1024; s++) acc += sc[hh][s] * pv[((size_t)b * SS + s) * 64 + d];
    acc /= redsum[hh];
    float p0 = acc * W1[t * 2 + 0];
    float p1 = acc * W1[t * 2 + 1];
    r0[t] = p0; r1[t] = p1;
    __syncthreads();
    for (int off = 128; off > 0; off >>= 1) {
        if (t < off) { r0[t] += r0[t + off]; r1[t] += r1[t + off]; }
        __syncthreads();
    }
    if (t == 0) {
        out[b * 2 + 0] = r0[0] + b1[0];
        out[b * 2 + 1] = r1[0] + b1[1];
    }
}

extern "C" void kernel_launch(void* const* d_in, const int* in_sizes, int n_in,
                              void* d_out, int out_size, void* d_ws, size_t ws_size,
                              hipStream_t stream) {
    const float* input = (const float*)d_in[0];
    const float* eWk = (const float*)d_in[3];
    const float* ebk = (const float*)d_in[4];
    const float* eWq = (const float*)d_in[5];
    const float* ebq = (const float*)d_in[6];
    const float* eWv = (const float*)d_in[7];
    const float* ebv = (const float*)d_in[8];
    const float* eWb = (const float*)d_in[9];
    const float* ebb = (const float*)d_in[10];
    const float* eWff = (const float*)d_in[11];
    const float* ebff = (const float*)d_in[12];
    const float* eg1 = (const float*)d_in[13];
    const float* ebe1 = (const float*)d_in[14];
    const float* pWk = (const float*)d_in[15];
    const float* pbk = (const float*)d_in[16];
    const float* pWv = (const float*)d_in[17];
    const float* pbv = (const float*)d_in[18];
    const float* qrs = (const float*)d_in[19];
    const float* W1 = (const float*)d_in[20];
    const float* b1 = (const float*)d_in[21];
    float* out = (float*)d_out;

    // ---- workspace layout (~135.7 MB)
    float* ws = (float*)d_ws;
    float* xbuf = ws;                               // MM*256 f32
    __bf16* xbf = (__bf16*)(xbuf + (size_t)MM * DD);      // MM*256 bf16
    float* tmp2 = (float*)(xbf + (size_t)MM * DD);        // MM*256 f32
    float* r3 = tmp2 + (size_t)MM * DD;             // 33.55MB region
    __bf16* vbf = (__bf16*)r3;                      //   vbf: MM*256 bf16 (attn phase)
    __bf16* vTb = vbf + (size_t)MM * DD;            //   vT:  B*256*1024 bf16 (attn phase)
    float* ffbuf = r3;                              //   ffbuf: MM*256 f32 (ff phase)
    float* r4 = r3 + (size_t)MM * DD;               // 16.78MB region
    __bf16* kbf = (__bf16*)r4;                      //   kbf: MM*64 (attn phase)
    __bf16* qbf = kbf + (size_t)MM * 64;            //   qbf: MM*64 (attn phase)
    __bf16* tmp2bf = (__bf16*)r4;                   //   tmp2bf: MM*256 (ff phase)
    float* bbuf = r4 + (size_t)MM * (DD / 2);       // MM f32
    __bf16* wbf = (__bf16*)(bbuf + MM);             // weights bf16: 675840 elems

    __bf16* WkT = wbf;                    // [4][64][256], pre-scaled by SC
    __bf16* WqT = WkT + 4 * 64 * 256;     // [4][64][256]
    __bf16* WvT = WqT + 4 * 64 * 256;     // [4][256][256]
    __bf16* WffT = WvT + 4 * 256 * 256;   // [4][256][256]
    __bf16* pWkT = WffT + 4 * 256 * 256;  // [16][256], pre-scaled by SC
    __bf16* pWvT = pWkT + 16 * 256;       // [64][256]

    float* pkbuf = tmp2;                  // after layer loop
    float* pvbuf = tmp2 + (size_t)MM * 16;

    const float SC = 0.125f;  // 1/sqrt(64)

    // ---- prep: weight transposes + input cast
    cast_wt<<<dim3(64, 1, 4), 256, 0, stream>>>(eWk, WkT, 64, SC);
    cast_wt<<<dim3(64, 1, 4), 256, 0, stream>>>(eWq, WqT, 64, 1.f);
    cast_wt<<<dim3(256, 1, 4), 256, 0, stream>>>(eWv, WvT, 256, 1.f);
    cast_wt<<<dim3(256, 1, 4), 256, 0, stream>>>(eWff, WffT, 256, 1.f);
    cast_wt<<<dim3(16, 1, 1), 256, 0, stream>>>(pWk, pWkT, 16, SC);
    cast_wt<<<dim3(64, 1, 1), 256, 0, stream>>>(pWv, pWvT, 64, 1.f);
    cast_x<<<MM * DD / (256 * 8), 256, 0, stream>>>(input, xbf);

    for (int l = 0; l < 4; l++) {
        const float* xin = (l == 0) ? input : xbuf;
        gemm_mfma<64, true><<<dim3(MM / 128, 1), 256, 0, stream>>>(
            xbf, WkT + (size_t)l * 64 * 256, ebk + l * 64, SC, 0, kbf, 64);
        gemm_mfma<64, true><<<dim3(MM / 128, 1), 256, 0, stream>>>(
            xbf, WqT + (size_t)l * 64 * 256, ebq + l * 64, 1.f, 0, qbf, 64);
        gemm_mfma<128, true><<<dim3(MM / 128, 2), 256, 0, stream>>>(
            xbf, WvT + (size_t)l * 256 * 256, ebv + l * DD, 1.f, 0, vbf, 256);
        transpose_v<<<dim3(SS / 64, DD / 64, BB), 256, 0, stream>>>(vbf, vTb);
        bias_gemv<<<MM / 4, 256, 0, stream>>>(xin, eWb + (size_t)l * DD, ebb + l, bbuf);
        attn_mfma<<<dim3(512, 1), 256, 0, stream>>>(kbf, qbf, vTb, bbuf, tmp2);
        ln_kernel<<<MM / 4, 256, 0, stream>>>(xin, tmp2, eg1 + l * DD, ebe1 + l * DD, tmp2, tmp2bf);
        gemm_mfma<128, false><<<dim3(MM / 128, 2), 256, 0, stream>>>(
            tmp2bf, WffT + (size_t)l * 256 * 256, ebff + l * DD, 1.f, 1, ffbuf, 256);
        ln_kernel<<<MM / 4, 256, 0, stream>>>(tmp2, ffbuf, nullptr, nullptr, xbuf, xbf);
    }
    gemm_mfma<16, false><<<dim3(MM / 128, 1), 256, 0, stream>>>(xbf, pWkT, pbk, SC, 0, pkbuf, 16);
    gemm_mfma<64, false><<<dim3(MM / 128, 1), 256, 0, stream>>>(xbf, pWvT, pbv, 1.f, 0, pvbuf, 64);
    pool_kernel<<<BB, 256, 0, stream>>>(pkbuf, pvbuf, qrs, W1, b1, out);
}

// Round 4
// 538.794 us; speedup vs baseline: 5.1474x; 1.2240x over previous
//
#include <hip/hip_runtime.h>
#include <hip/hip_bf16.h>
#include <math.h>

#define BB 32
#define SS 1024
#define DD 256
#define MM (BB*SS)   // 32768
#define LEPS 1e-5f

typedef __bf16 bf16x8 __attribute__((ext_vector_type(8)));
typedef __bf16 bf16x4 __attribute__((ext_vector_type(4)));
typedef float f32x4 __attribute__((ext_vector_type(4)));

// ---------------- weight cast+transpose: WT[l][n][k] = W[l][k][n]*scale (fp32->bf16), K=256
__global__ __launch_bounds__(256) void cast_wt(const float* __restrict__ W,
                                               __bf16* __restrict__ WT,
                                               int N, float scale) {
    int n = blockIdx.x, l = blockIdx.z, k = threadIdx.x;
    size_t stride = (size_t)256 * N;
    WT[stride * l + (size_t)n * 256 + k] = (__bf16)(W[stride * l + (size_t)k * N + n] * scale);
}

// ---------------- cast fp32 -> bf16, 8 elems/thread
__global__ __launch_bounds__(256) void cast_x(const float* __restrict__ x, __bf16* __restrict__ xb) {
    size_t i = ((size_t)blockIdx.x * 256 + threadIdx.x) * 8;
    float4 a = *(const float4*)(x + i);
    float4 b = *(const float4*)(x + i + 4);
    __bf16 o[8] __attribute__((aligned(16)));
    o[0] = (__bf16)a.x; o[1] = (__bf16)a.y; o[2] = (__bf16)a.z; o[3] = (__bf16)a.w;
    o[4] = (__bf16)b.x; o[5] = (__bf16)b.y; o[6] = (__bf16)b.z; o[7] = (__bf16)b.w;
    *(bf16x8*)(xb + i) = *(bf16x8*)o;
}

// ---------------- MFMA GEMM: C[M,N] = A[M,256] @ WT[N,256]^T + bias*bscale, opt relu
template <int BN, bool OBF>
__global__ __launch_bounds__(256) void gemm_mfma(const __bf16* __restrict__ A,
                                                 const __bf16* __restrict__ WT,
                                                 const float* __restrict__ bias,
                                                 float bscale, int relu,
                                                 void* __restrict__ Cv, int N) {
    constexpr int MR = (BN == 128) ? 4 : 2;
    constexpr int NC = (BN == 128) ? 4 : BN / 16;
    const int t = threadIdx.x;
    const int w = t >> 6, lane = t & 63;
    const int m0 = blockIdx.x * 128;
    const int n0 = blockIdx.y * BN;
    const int wr = (BN == 128) ? (w >> 1) * 64 : w * 32;
    const int wc = (BN == 128) ? (w & 1) * 64 : 0;
    __shared__ __align__(16) __bf16 Al[128][64];
    __shared__ __align__(16) __bf16 Wl[BN][64];
    f32x4 acc[MR][NC] = {};

    for (int k0 = 0; k0 < 256; k0 += 64) {
        __syncthreads();
        {
            int r = t >> 1, half = t & 1;
            const __bf16* src = A + (size_t)(m0 + r) * 256 + k0 + half * 32;
            bf16x8 v0 = *(const bf16x8*)(src);
            bf16x8 v1 = *(const bf16x8*)(src + 8);
            bf16x8 v2 = *(const bf16x8*)(src + 16);
            bf16x8 v3 = *(const bf16x8*)(src + 24);
            int cb = half * 4;
            *(bf16x8*)&Al[r][((cb + 0) ^ (r & 7)) * 8] = v0;
            *(bf16x8*)&Al[r][((cb + 1) ^ (r & 7)) * 8] = v1;
            *(bf16x8*)&Al[r][((cb + 2) ^ (r & 7)) * 8] = v2;
            *(bf16x8*)&Al[r][((cb + 3) ^ (r & 7)) * 8] = v3;
        }
        if (BN == 128) {
            int r = t >> 1, half = t & 1;
            const __bf16* src = WT + (size_t)(n0 + r) * 256 + k0 + half * 32;
            bf16x8 v0 = *(const bf16x8*)(src);
            bf16x8 v1 = *(const bf16x8*)(src + 8);
            bf16x8 v2 = *(const bf16x8*)(src + 16);
            bf16x8 v3 = *(const bf16x8*)(src + 24);
            int cb = half * 4;
            *(bf16x8*)&Wl[r][((cb + 0) ^ (r & 7)) * 8] = v0;
            *(bf16x8*)&Wl[r][((cb + 1) ^ (r & 7)) * 8] = v1;
            *(bf16x8*)&Wl[r][((cb + 2) ^ (r & 7)) * 8] = v2;
            *(bf16x8*)&Wl[r][((cb + 3) ^ (r & 7)) * 8] = v3;
        } else if (BN == 64) {
            int n = t >> 2, q = t & 3;
            const __bf16* src = WT + (size_t)(n0 + n) * 256 + k0 + q * 16;
            bf16x8 v0 = *(const bf16x8*)src;
            bf16x8 v1 = *(const bf16x8*)(src + 8);
            *(bf16x8*)&Wl[n][((q * 2 + 0) ^ (n & 7)) * 8] = v0;
            *(bf16x8*)&Wl[n][((q * 2 + 1) ^ (n & 7)) * 8] = v1;
        } else {
            if (t < 128) {
                int n = t >> 3, c = t & 7;
                bf16x8 v = *(const bf16x8*)(WT + (size_t)(n0 + n) * 256 + k0 + c * 8);
                *(bf16x8*)&Wl[n][(c ^ (n & 7)) * 8] = v;
            }
        }
        __syncthreads();
#pragma unroll
        for (int ks = 0; ks < 2; ks++) {
            int c = ks * 4 + (lane >> 4);
            bf16x8 af[MR];
#pragma unroll
            for (int mf = 0; mf < MR; mf++) {
                int i = wr + mf * 16 + (lane & 15);
                af[mf] = *(const bf16x8*)&Al[i][(c ^ (i & 7)) * 8];
            }
#pragma unroll
            for (int nf = 0; nf < NC; nf++) {
                int n = wc + nf * 16 + (lane & 15);
                bf16x8 bfr = *(const bf16x8*)&Wl[n][(c ^ (n & 7)) * 8];
#pragma unroll
                for (int mf = 0; mf < MR; mf++)
                    acc[mf][nf] = __builtin_amdgcn_mfma_f32_16x16x32_bf16(af[mf], bfr, acc[mf][nf], 0, 0, 0);
            }
        }
    }
#pragma unroll
    for (int mf = 0; mf < MR; mf++) {
#pragma unroll
        for (int nf = 0; nf < NC; nf++) {
            int col = n0 + wc + nf * 16 + (lane & 15);
            float bz = bias[col] * bscale;
#pragma unroll
            for (int r = 0; r < 4; r++) {
                int row = m0 + wr + mf * 16 + (lane >> 4) * 4 + r;
                float v = acc[mf][nf][r] + bz;
                if (relu) v = fmaxf(v, 0.f);
                if (OBF) ((__bf16*)Cv)[(size_t)row * N + col] = (__bf16)v;
                else ((float*)Cv)[(size_t)row * N + col] = v;
            }
        }
    }
}

// ---------------- transpose+pack: vT[b][d][s] = vb[b][s][d]  (bf16 -> bf16)
__global__ __launch_bounds__(256) void transpose_v(const __bf16* __restrict__ vb,
                                                   __bf16* __restrict__ vT) {
    const int b = blockIdx.z, d0 = blockIdx.y * 64, s0 = blockIdx.x * 64;
    const int t = threadIdx.x;
    __shared__ __align__(16) __bf16 Ts[64][64];
    {
        int s = t >> 2, c0 = (t & 3) * 2;
        const __bf16* src = vb + ((size_t)(b * SS + s0 + s)) * DD + d0 + c0 * 8;
        bf16x8 v0 = *(const bf16x8*)src;
        bf16x8 v1 = *(const bf16x8*)(src + 8);
        *(bf16x8*)&Ts[s][((c0 + 0) ^ (s & 7)) * 8] = v0;
        *(bf16x8*)&Ts[s][((c0 + 1) ^ (s & 7)) * 8] = v1;
    }
    __syncthreads();
    {
        int dr = t >> 2, sc = (t & 3) * 16;
        __bf16 o[16] __attribute__((aligned(16)));
#pragma unroll
        for (int u = 0; u < 16; u++) {
            int row = sc + u;
            o[u] = Ts[row][((dr >> 3) ^ (row & 7)) * 8 + (dr & 7)];
        }
        __bf16* dst = vT + ((size_t)(b * DD + d0 + dr)) * SS + s0 + sc;
        *(bf16x8*)dst = *(bf16x8*)&o[0];
        *(bf16x8*)(dst + 8) = *(bf16x8*)&o[8];
    }
}

// ---------------- bias gemv: out[r] = x[r,:] . Wb[:,0] + bb[0]
__global__ __launch_bounds__(256) void bias_gemv(const float* __restrict__ X,
                                                 const float* __restrict__ Wb,
                                                 const float* __restrict__ bb,
                                                 float* __restrict__ out) {
    int wave = threadIdx.x >> 6, lane = threadIdx.x & 63;
    size_t row = (size_t)blockIdx.x * 4 + wave;
    float4 xv = *(const float4*)(X + row * 256 + lane * 4);
    float4 wv = *(const float4*)(Wb + lane * 4);
    float p = xv.x * wv.x + xv.y * wv.y + xv.z * wv.z + xv.w * wv.w;
    for (int off = 32; off; off >>= 1) p += __shfl_down(p, off, 64);
    if (lane == 0) out[row] = p + bb[0];
}

// ---------------- MFMA fused attention + LN1 (8 waves, j-tile 64)
// tmp2 = LN(x + Sig(KQ^T + bias) @ V) * gamma + beta, also bf16 copy
__global__ __launch_bounds__(512, 4) void attn_mfma(const __bf16* __restrict__ kb,
                                                    const __bf16* __restrict__ qb,
                                                    const __bf16* __restrict__ vT,
                                                    const float* __restrict__ biasb,
                                                    const float* __restrict__ xin,
                                                    const float* __restrict__ gamma,
                                                    const float* __restrict__ beta,
                                                    float* __restrict__ outf,
                                                    __bf16* __restrict__ outb) {
    int h = blockIdx.x;
    int blow = h & 7, rest = h >> 3;
    int ib = rest & 15;
    int b = blow + (rest >> 4) * 8;
    const int i0 = ib * 64;
    const int t = threadIdx.x;
    const int w = t >> 6, lane = t & 63;
    const int iq = w >> 1;        // 0..3: row group iq*16
    const int dhalf = w & 1;      // PV: d-half (0..127 / 128..255)

    __shared__ __align__(16) __bf16 Kl[64][64];   // [i][8 chunks of 8 k], chunk ^= (i&7)
    __shared__ __align__(16) __bf16 Ql[64][64];   // [j][8 chunks of 8 k], chunk ^= (j&7)
    __shared__ __align__(16) __bf16 Vl[256][64];  // [d][8 chunks of 8 j], chunk ^= (d&7)
    __shared__ __align__(16) __bf16 Sl[64][64];   // [i][8 chunks of 8 j], chunk ^= (i&7)
    __shared__ float bsh[64];
    __shared__ float rowred[2][64][2];            // [dhalf][row][{sum,ssq}]

    {   // stage K once: 64 rows x 8 chunks = 512 threads
        int i = t >> 3, c = t & 7;
        bf16x8 v = *(const bf16x8*)(kb + ((size_t)(b * SS + i0 + i)) * 64 + c * 8);
        *(bf16x8*)&Kl[i][(c ^ (i & 7)) * 8] = v;
        if (t < 64) bsh[t] = biasb[b * SS + i0 + t];
    }

    f32x4 acc[8] = {};  // [dq]: rows iq*16.., col dhalf*128 + dq*16 + (lane&15)

    for (int j0 = 0; j0 < SS; j0 += 64) {
        __syncthreads();
        {   // stage Q tile [64][64]
            int j = t >> 3, c = t & 7;
            bf16x8 v = *(const bf16x8*)(qb + ((size_t)(b * SS + j0 + j)) * 64 + c * 8);
            *(bf16x8*)&Ql[j][(c ^ (j & 7)) * 8] = v;
        }
        {   // stage vT tile [256][64]: thread -> d = t>>1, j-half = t&1
            int d = t >> 1, jh = t & 1;
            const __bf16* src = vT + ((size_t)b * 256 + d) * SS + j0 + jh * 32;
#pragma unroll
            for (int u = 0; u < 4; u++) {
                bf16x8 v = *(const bf16x8*)(src + u * 8);
                *(bf16x8*)&Vl[d][((jh * 4 + u) ^ (d & 7)) * 8] = v;
            }
        }
        __syncthreads();
        // ---- S phase: wave w computes tiles (iq, jq) for jq in {2*(w&1), 2*(w&1)+1}
#pragma unroll
        for (int jj = 0; jj < 2; jj++) {
            int jq = (w & 1) * 2 + jj;
            f32x4 sacc = {0.f, 0.f, 0.f, 0.f};
#pragma unroll
            for (int ks = 0; ks < 2; ks++) {
                int i = iq * 16 + (lane & 15);
                int ck = ks * 4 + (lane >> 4);
                bf16x8 a = *(const bf16x8*)&Kl[i][(ck ^ (i & 7)) * 8];
                int j = jq * 16 + (lane & 15);
                bf16x8 bq = *(const bf16x8*)&Ql[j][(ck ^ (j & 7)) * 8];
                sacc = __builtin_amdgcn_mfma_f32_16x16x32_bf16(a, bq, sacc, 0, 0, 0);
            }
            int jcol = jq * 16 + (lane & 15);
#pragma unroll
            for (int r = 0; r < 4; r++) {
                int irow = iq * 16 + (lane >> 4) * 4 + r;
                float x = sacc[r] + bsh[irow];
                float sg = 1.f / (1.f + __expf(-x));
                Sl[irow][(((jcol >> 3) ^ (irow & 7)) * 8) + (jcol & 7)] = (__bf16)sg;
            }
        }
        __syncthreads();
        // ---- PV phase: wave w owns rows iq*16..+16, cols dhalf*128..+128
        bf16x8 am[2];
#pragma unroll
        for (int m = 0; m < 2; m++) {
            int i = iq * 16 + (lane & 15);
            int cj = m * 4 + (lane >> 4);
            am[m] = *(const bf16x8*)&Sl[i][(cj ^ (i & 7)) * 8];
        }
#pragma unroll
        for (int dq = 0; dq < 8; dq++) {
            int d = dhalf * 128 + dq * 16 + (lane & 15);
#pragma unroll
            for (int m = 0; m < 2; m++) {
                int cj = m * 4 + (lane >> 4);
                bf16x8 bv = *(const bf16x8*)&Vl[d][(cj ^ (d & 7)) * 8];
                acc[dq] = __builtin_amdgcn_mfma_f32_16x16x32_bf16(am[m], bv, acc[dq], 0, 0, 0);
            }
        }
    }

    // ---- fused LN1 epilogue: rows iq*16 + (lane>>4)*4 + r, cols dhalf*128 + dq*16 + (lane&15)
    // add residual x into acc
#pragma unroll
    for (int r = 0; r < 4; r++) {
        int il = iq * 16 + (lane >> 4) * 4 + r;
        size_t rowoff = ((size_t)(b * SS + i0 + il)) * 256 + dhalf * 128 + (lane & 15);
#pragma unroll
        for (int dq = 0; dq < 8; dq++)
            acc[dq][r] += xin[rowoff + dq * 16];
    }
    // per-row partial sums over this lane's 8 cols; reduce across 16-lane col group
    float sr[4], qr[4];
#pragma unroll
    for (int r = 0; r < 4; r++) {
        float s = 0.f, q = 0.f;
#pragma unroll
        for (int dq = 0; dq < 8; dq++) {
            float v = acc[dq][r];
            s += v; q += v * v;
        }
#pragma unroll
        for (int mask = 8; mask; mask >>= 1) {
            s += __shfl_xor(s, mask, 64);
            q += __shfl_xor(q, mask, 64);
        }
        sr[r] = s; qr[r] = q;
    }
    if ((lane & 15) == 0) {
#pragma unroll
        for (int r = 0; r < 4; r++) {
            int il = iq * 16 + (lane >> 4) * 4 + r;
            rowred[dhalf][il][0] = sr[r];
            rowred[dhalf][il][1] = qr[r];
        }
    }
    __syncthreads();
    // gamma/beta for this lane's cols
    float gv[8], bv2[8];
#pragma unroll
    for (int dq = 0; dq < 8; dq++) {
        int d = dhalf * 128 + dq * 16 + (lane & 15);
        gv[dq] = gamma[d];
        bv2[dq] = beta[d];
    }
#pragma unroll
    for (int r = 0; r < 4; r++) {
        int il = iq * 16 + (lane >> 4) * 4 + r;
        float st = rowred[0][il][0] + rowred[1][il][0];
        float qt = rowred[0][il][1] + rowred[1][il][1];
        float mean = st * (1.f / 256.f);
        float var = qt * (1.f / 256.f) - mean * mean;
        float inv = 1.f / sqrtf(var + LEPS);
        size_t rowoff = ((size_t)(b * SS + i0 + il)) * 256 + dhalf * 128 + (lane & 15);
#pragma unroll
        for (int dq = 0; dq < 8; dq++) {
            float o = (acc[dq][r] - mean) * inv * gv[dq] + bv2[dq];
            outf[rowoff + dq * 16] = o;
            outb[rowoff + dq * 16] = (__bf16)o;
        }
    }
}

// ---------------- LN2: out = LN(A + Badd_bf16), no affine; dual fp32 + bf16 store
__global__ __launch_bounds__(256) void ln2_kernel(const float* __restrict__ A,
                                                  const __bf16* __restrict__ Badd,
                                                  float* __restrict__ out,
                                                  __bf16* __restrict__ outb) {
    int wave = threadIdx.x >> 6, lane = threadIdx.x & 63;
    size_t row = (size_t)blockIdx.x * 4 + wave;
    float4 av = *(const float4*)(A + row * 256 + lane * 4);
    bf16x4 bv = *(const bf16x4*)(Badd + row * 256 + lane * 4);
    float x0 = av.x + (float)bv[0], x1 = av.y + (float)bv[1];
    float x2 = av.z + (float)bv[2], x3 = av.w + (float)bv[3];
    float s = x0 + x1 + x2 + x3;
    float ss = x0 * x0 + x1 * x1 + x2 * x2 + x3 * x3;
    for (int off = 32; off; off >>= 1) {
        s += __shfl_down(s, off, 64);
        ss += __shfl_down(ss, off, 64);
    }
    s = __shfl(s, 0, 64);
    ss = __shfl(ss, 0, 64);
    float mean = s * (1.f / 256.f);
    float var = ss * (1.f / 256.f) - mean * mean;
    float inv = 1.f / sqrtf(var + LEPS);
    float4 o;
    o.x = (x0 - mean) * inv; o.y = (x1 - mean) * inv;
    o.z = (x2 - mean) * inv; o.w = (x3 - mean) * inv;
    *(float4*)(out + row * 256 + lane * 4) = o;
    __bf16 ob[4] __attribute__((aligned(8)));
    ob[0] = (__bf16)o.x; ob[1] = (__bf16)o.y; ob[2] = (__bf16)o.z; ob[3] = (__bf16)o.w;
    *(uint2*)(outb + row * 256 + lane * 4) = *(uint2*)ob;
}

// ---------------- pooling (unchanged)
__global__ __launch_bounds__(256) void pool_kernel(const float* __restrict__ pk,
                                                   const float* __restrict__ pv,
                                                   const float* __restrict__ queries,
                                                   const float* __restrict__ W1,
                                                   const float* __restrict__ b1,
                                                   float* __restrict__ out) {
    const int b = blockIdx.x;
    const int t = threadIdx.x;
    __shared__ float sc[4][1024];
    __shared__ float qv[4][16];
    __shared__ float redsum[4];
    __shared__ float r0[256], r1[256];
    if (t < 64) qv[t >> 4][t & 15] = queries[t];
    __syncthreads();
    for (int c = 0; c < 4; c++) {
        int s = c * 256 + t;
        const float* p = pk + ((size_t)b * SS + s) * 16;
        float4 a0 = *(const float4*)p;
        float4 a1 = *(const float4*)(p + 4);
        float4 a2 = *(const float4*)(p + 8);
        float4 a3 = *(const float4*)(p + 12);
#pragma unroll
        for (int hh = 0; hh < 4; hh++) {
            float d = a0.x * qv[hh][0] + a0.y * qv[hh][1] + a0.z * qv[hh][2] + a0.w * qv[hh][3]
                    + a1.x * qv[hh][4] + a1.y * qv[hh][5] + a1.z * qv[hh][6] + a1.w * qv[hh][7]
                    + a2.x * qv[hh][8] + a2.y * qv[hh][9] + a2.z * qv[hh][10] + a2.w * qv[hh][11]
                    + a3.x * qv[hh][12] + a3.y * qv[hh][13] + a3.z * qv[hh][14] + a3.w * qv[hh][15];
            sc[hh][s] = d;
        }
    }
    __syncthreads();
    {
        int hh = t >> 6, lane = t & 63;
        float m = -1e30f;
        for (int s = lane; s < 1024; s += 64) m = fmaxf(m, sc[hh][s]);
        for (int off = 32; off; off >>= 1) m = fmaxf(m, __shfl_down(m, off, 64));
        m = __shfl(m, 0, 64);
        float sum = 0.f;
        for (int s = lane; s < 1024; s += 64) {
            float e = expf(sc[hh][s] - m);
            sc[hh][s] = e;
            sum += e;
        }
        for (int off = 32; off; off >>= 1) sum += __shfl_down(sum, off, 64);
        if (lane == 0) redsum[hh] = sum;
    }
    __syncthreads();
    int hh = t >> 6, d = t & 63;
    float acc = 0.f;
    for (int s = 0; s < 1024; s++) acc += sc[hh][s] * pv[((size_t)b * SS + s) * 64 + d];
    acc /= redsum[hh];
    float p0 = acc * W1[t * 2 + 0];
    float p1 = acc * W1[t * 2 + 1];
    r0[t] = p0; r1[t] = p1;
    __syncthreads();
    for (int off = 128; off > 0; off >>= 1) {
        if (t < off) { r0[t] += r0[t + off]; r1[t] += r1[t + off]; }
        __syncthreads();
    }
    if (t == 0) {
        out[b * 2 + 0] = r0[0] + b1[0];
        out[b * 2 + 1] = r1[0] + b1[1];
    }
}

extern "C" void kernel_launch(void* const* d_in, const int* in_sizes, int n_in,
                              void* d_out, int out_size, void* d_ws, size_t ws_size,
                              hipStream_t stream) {
    const float* input = (const float*)d_in[0];
    const float* eWk = (const float*)d_in[3];
    const float* ebk = (const float*)d_in[4];
    const float* eWq = (const float*)d_in[5];
    const float* ebq = (const float*)d_in[6];
    const float* eWv = (const float*)d_in[7];
    const float* ebv = (const float*)d_in[8];
    const float* eWb = (const float*)d_in[9];
    const float* ebb = (const float*)d_in[10];
    const float* eWff = (const float*)d_in[11];
    const float* ebff = (const float*)d_in[12];
    const float* eg1 = (const float*)d_in[13];
    const float* ebe1 = (const float*)d_in[14];
    const float* pWk = (const float*)d_in[15];
    const float* pbk = (const float*)d_in[16];
    const float* pWv = (const float*)d_in[17];
    const float* pbv = (const float*)d_in[18];
    const float* qrs = (const float*)d_in[19];
    const float* W1 = (const float*)d_in[20];
    const float* b1 = (const float*)d_in[21];
    float* out = (float*)d_out;

    // ---- workspace layout (~135.7 MB), phase-based aliasing
    float* ws = (float*)d_ws;
    float* xbuf = ws;                               // MM*256 f32
    __bf16* xbf = (__bf16*)(xbuf + (size_t)MM * DD);      // MM*256 bf16
    float* tmp2 = (float*)(xbf + (size_t)MM * DD);        // MM*256 f32 (LN1 out, residual)
    float* r3 = tmp2 + (size_t)MM * DD;             // 33.55MB region
    __bf16* vbf = (__bf16*)r3;                      //   v row-major (pre-transpose); dead after transpose_v
    __bf16* tmp2bf = (__bf16*)r3;                   //   = vbf region: LN1 bf16 out (attn epilogue)
    __bf16* vTb = vbf + (size_t)MM * DD;            //   vT (live through attn)
    __bf16* ffbf = vTb;                             //   = vTb region: ff bf16 out (after attn)
    float* r4 = r3 + (size_t)MM * DD;               // 16.78MB region
    __bf16* kbf = (__bf16*)r4;                      //   k bf16
    __bf16* qbf = kbf + (size_t)MM * 64;            //   q bf16
    float* bbuf = r4 + (size_t)MM * (DD / 2);       // MM f32 (after kbf+qbf)
    __bf16* wbf = (__bf16*)(bbuf + MM);             // weights bf16

    __bf16* WkT = wbf;                    // [4][64][256], pre-scaled by SC
    __bf16* WqT = WkT + 4 * 64 * 256;
    __bf16* WvT = WqT + 4 * 64 * 256;
    __bf16* WffT = WvT + 4 * 256 * 256;
    __bf16* pWkT = WffT + 4 * 256 * 256;  // [16][256], pre-scaled
    __bf16* pWvT = pWkT + 16 * 256;       // [64][256]

    float* pkbuf = tmp2;                  // tail phase
    float* pvbuf = tmp2 + (size_t)MM * 16;

    const float SC = 0.125f;  // 1/sqrt(64)

    cast_wt<<<dim3(64, 1, 4), 256, 0, stream>>>(eWk, WkT, 64, SC);
    cast_wt<<<dim3(64, 1, 4), 256, 0, stream>>>(eWq, WqT, 64, 1.f);
    cast_wt<<<dim3(256, 1, 4), 256, 0, stream>>>(eWv, WvT, 256, 1.f);
    cast_wt<<<dim3(256, 1, 4), 256, 0, stream>>>(eWff, WffT, 256, 1.f);
    cast_wt<<<dim3(16, 1, 1), 256, 0, stream>>>(pWk, pWkT, 16, SC);
    cast_wt<<<dim3(64, 1, 1), 256, 0, stream>>>(pWv, pWvT, 64, 1.f);
    cast_x<<<MM * DD / (256 * 8), 256, 0, stream>>>(input, xbf);

    for (int l = 0; l < 4; l++) {
        const float* xin = (l == 0) ? input : xbuf;
        gemm_mfma<64, true><<<dim3(MM / 128, 1), 256, 0, stream>>>(
            xbf, WkT + (size_t)l * 64 * 256, ebk + l * 64, SC, 0, kbf, 64);
        gemm_mfma<64, true><<<dim3(MM / 128, 1), 256, 0, stream>>>(
            xbf, WqT + (size_t)l * 64 * 256, ebq + l * 64, 1.f, 0, qbf, 64);
        gemm_mfma<128, true><<<dim3(MM / 128, 2), 256, 0, stream>>>(
            xbf, WvT + (size_t)l * 256 * 256, ebv + l * DD, 1.f, 0, vbf, 256);
        transpose_v<<<dim3(SS / 64, DD / 64, BB), 256, 0, stream>>>(vbf, vTb);
        bias_gemv<<<MM / 4, 256, 0, stream>>>(xin, eWb + (size_t)l * DD, ebb + l, bbuf);
        attn_mfma<<<dim3(512, 1), 512, 0, stream>>>(kbf, qbf, vTb, bbuf, xin,
                                                    eg1 + l * DD, ebe1 + l * DD, tmp2, tmp2bf);
        gemm_mfma<128, true><<<dim3(MM / 128, 2), 256, 0, stream>>>(
            tmp2bf, WffT + (size_t)l * 256 * 256, ebff + l * DD, 1.f, 1, ffbf, 256);
        ln2_kernel<<<MM / 4, 256, 0, stream>>>(tmp2, ffbf, xbuf, xbf);
    }
    gemm_mfma<16, false><<<dim3(MM / 128, 1), 256, 0, stream>>>(xbf, pWkT, pbk, SC, 0, pkbuf, 16);
    gemm_mfma<64, false><<<dim3(MM / 128, 1), 256, 0, stream>>>(xbf, pWvT, pbv, 1.f, 0, pvbuf, 64);
    pool_kernel<<<BB, 256, 0, stream>>>(pkbuf, pvbuf, qrs, W1, b1, out);
}